// Round 8
// baseline (430.106 us; speedup 1.0000x reference)
//
#include <hip/hip_runtime.h>

// Problem constants (fixed by setup_inputs)
#define BATCH    4
#define NQ       10000
#define EMB      256
#define NH       8
#define DH       32
#define NL       4
#define NP       8
#define S_TOTAL  19560
#define NROW     (BATCH * NQ)          // 40000
#define VROWS    (BATCH * S_TOTAL)     // 78240

typedef _Float16 half8 __attribute__((ext_vector_type(8)));
typedef _Float16 half4v __attribute__((ext_vector_type(4)));
typedef _Float16 half2v __attribute__((ext_vector_type(2)));
typedef float floatx4 __attribute__((ext_vector_type(4)));
typedef float floatx2 __attribute__((ext_vector_type(2)));
typedef int intx4 __attribute__((ext_vector_type(4)));
typedef int intx2 __attribute__((ext_vector_type(2)));

// ---------------------------------------------------------------------------
// One-shot weight prep: transpose+swizzle all three weight matrices to f16.
// Logical row n (0..1023): [0,512) w_off -> wT768, [512,768) w_attn -> wT768,
// [768,1024) w_val (256 rows) -> wvaT. Swizzle: 16B chunk c of row n lands at
// chunk c ^ (n&7).
// ---------------------------------------------------------------------------
__global__ __launch_bounds__(256) void prep_weights(
    const float* __restrict__ w_off, const float* __restrict__ w_attn,
    const float* __restrict__ w_val, _Float16* __restrict__ wT768,
    _Float16* __restrict__ wvaT) {
  const int tid = blockIdx.x * 256 + threadIdx.x;   // over 1024*256
  const int n = tid >> 8, k = tid & 255;
  const int c = k >> 3, e = k & 7;
  const int swz = ((c ^ (n & 7)) << 3) + e;
  float v;
  _Float16* dst;
  if (n < 512)      { v = __builtin_nontemporal_load(&w_off[(size_t)k * 512 + n]);          dst = wT768 + (size_t)n * 256; }
  else if (n < 768) { v = __builtin_nontemporal_load(&w_attn[(size_t)k * 256 + (n - 512)]); dst = wT768 + (size_t)n * 256; }
  else              { v = __builtin_nontemporal_load(&w_val[(size_t)k * 256 + (n - 768)]);  dst = wvaT + (size_t)(n - 768) * 256; }
  dst[swz] = (_Float16)v;   // wT IS re-read by gemms: temporal store
}

// ---------------------------------------------------------------------------
// MFMA GEMM body (device fn): A-register-resident + B-chunk-in-LDS.
//   C = A[M,256]_f32 @ WTs[NC,256]^T + bias(col-select)
// Register-prefetch double-buffer; SWZ path uses swapped-operand MFMA so the
// 4 acc regs land on 4 consecutive channels -> coalesced 8B half4 stores.
// Round-15: nt hints — A-stream loads and output stores are read/write-once
// (no reuse): mark non-temporal so they don't evict B-tiles / vh from L2.
// ---------------------------------------------------------------------------
template <int NC, int NYS, bool SWZ>
__device__ __forceinline__ void gemm_body(
    const float* __restrict__ A, const _Float16* __restrict__ WTs,
    const float* __restrict__ bias0, const float* __restrict__ bias1,
    int splitc, _Float16* __restrict__ C, int M, int bx, int by,
    _Float16* bsm /* 64*256 LDS */) {
  const int t = threadIdx.x;
  const int wave = t >> 6, lane = t & 63;
  const int l15 = lane & 15, quad = lane >> 4;
  const int m0 = bx * 128 + wave * 32;
  const int nlo = by * (NC / NYS);
  const int nchunks = (NC / NYS) / 64;

  const _Float16* src = WTs + (size_t)nlo * 256;

  // ---- issue chunk-0 B loads first (latency covered by A load+convert) ----
  half8 pb[8];
  #pragma unroll
  for (int i = 0; i < 8; ++i)
    pb[i] = *(const half8*)(src + t * 8 + i * 2048);

  // ---- load + convert the wave's A slice (32 rows x 256) ----
  half8 a[2][8];
  #pragma unroll
  for (int i = 0; i < 2; ++i) {
    const float* Ar = A + (size_t)min(m0 + 16 * i + l15, M - 1) * 256 + quad * 8;
    #pragma unroll
    for (int ks = 0; ks < 8; ++ks) {
      const floatx4 f0 = __builtin_nontemporal_load((const floatx4*)(Ar + ks * 32));
      const floatx4 f1 = __builtin_nontemporal_load((const floatx4*)(Ar + ks * 32 + 4));
      a[i][ks][0] = (_Float16)f0[0]; a[i][ks][1] = (_Float16)f0[1];
      a[i][ks][2] = (_Float16)f0[2]; a[i][ks][3] = (_Float16)f0[3];
      a[i][ks][4] = (_Float16)f1[0]; a[i][ks][5] = (_Float16)f1[1];
      a[i][ks][6] = (_Float16)f1[2]; a[i][ks][7] = (_Float16)f1[3];
    }
  }

  #pragma unroll
  for (int i = 0; i < 8; ++i)
    *(half8*)&bsm[t * 8 + i * 2048] = pb[i];
  __syncthreads();

  for (int ch = 0; ch < nchunks; ++ch) {
    // prefetch next chunk into registers (overlaps with compute below)
    if (ch + 1 < nchunks) {
      const _Float16* s2 = src + (size_t)(ch + 1) * 64 * 256;
      #pragma unroll
      for (int i = 0; i < 8; ++i)
        pb[i] = *(const half8*)(s2 + t * 8 + i * 2048);
    }

    floatx4 acc[2][4] = {};
    #pragma unroll
    for (int ks = 0; ks < 8; ++ks) {
      half8 b[4];
      #pragma unroll
      for (int j = 0; j < 4; ++j)
        b[j] = *(const half8*)&bsm[(16 * j + l15) * 256 +
                                   ((((ks * 4 + quad) ^ (l15 & 7))) << 3)];
      if constexpr (SWZ) {
        #pragma unroll
        for (int j = 0; j < 4; ++j)
          #pragma unroll
          for (int i = 0; i < 2; ++i)
            acc[i][j] = __builtin_amdgcn_mfma_f32_16x16x32_f16(b[j], a[i][ks], acc[i][j], 0, 0, 0);
      } else {
        #pragma unroll
        for (int j = 0; j < 4; ++j)
          #pragma unroll
          for (int i = 0; i < 2; ++i)
            acc[i][j] = __builtin_amdgcn_mfma_f32_16x16x32_f16(a[i][ks], b[j], acc[i][j], 0, 0, 0);
      }
    }

    const int nc0 = nlo + ch * 64;

    if constexpr (SWZ) {
      #pragma unroll
      for (int j = 0; j < 4; ++j) {
        const int col0 = nc0 + 16 * j + quad * 4;
        const int h = col0 >> 5, c0 = col0 & 31;
        const floatx4 bq = *(const floatx4*)(bias0 + col0);
        #pragma unroll
        for (int i = 0; i < 2; ++i) {
          const int row = m0 + 16 * i + l15;
          if (row < M) {
            const int b = row / S_TOTAL;
            const int s = row - b * S_TOTAL;
            half4v pk;
            pk[0] = (_Float16)(acc[i][j][0] + bq[0]);
            pk[1] = (_Float16)(acc[i][j][1] + bq[1]);
            pk[2] = (_Float16)(acc[i][j][2] + bq[2]);
            pk[3] = (_Float16)(acc[i][j][3] + bq[3]);
            __builtin_nontemporal_store(
                pk, (half4v*)(C + ((((size_t)b * NH + h) * S_TOTAL + s) * 32 + c0)));
          }
        }
      }
    } else {
      float bc[4];
      #pragma unroll
      for (int j = 0; j < 4; ++j) {
        const int col = nc0 + 16 * j + l15;
        bc[j] = (col < splitc) ? bias0[col] : bias1[col - splitc];
      }
      #pragma unroll
      for (int i = 0; i < 2; ++i) {
        #pragma unroll
        for (int r = 0; r < 4; ++r) {
          const int row = m0 + 16 * i + quad * 4 + r;
          if (row < M) {
            #pragma unroll
            for (int j = 0; j < 4; ++j)
              __builtin_nontemporal_store(
                  (_Float16)(acc[i][j][r] + bc[j]),
                  C + ((size_t)row * NC + nc0 + 16 * j + l15));
          }
        }
      }
    }

    __syncthreads();               // all waves done reading bsm
    if (ch + 1 < nchunks) {
      #pragma unroll
      for (int i = 0; i < 8; ++i)
        *(half8*)&bsm[t * 8 + i * 2048] = pb[i];
      __syncthreads();
    }
  }
}

#define VH_BLOCKS 612   // (78240+127)/128
#define FU_BLOCKS 313   // (40000+127)/128

__global__ __launch_bounds__(256, 3) void gemm_merged(
    const float* __restrict__ value, const float* __restrict__ query,
    const _Float16* __restrict__ wvaT, const _Float16* __restrict__ wT768,
    const float* __restrict__ b_val, const float* __restrict__ b_off,
    const float* __restrict__ b_attn,
    _Float16* __restrict__ vh, _Float16* __restrict__ fused_h) {
  __shared__ _Float16 bsm[64 * 256];   // 32 KB B chunk (swizzled rows)
  const int bid = blockIdx.x;
  if (bid < VH_BLOCKS) {
    gemm_body<256, 1, true>(value, wvaT, b_val, b_val, 1 << 30, vh, VROWS,
                            bid, 0, bsm);
  } else {
    const int r = bid - VH_BLOCKS;
    const int by = (r >= FU_BLOCKS) ? 1 : 0;
    const int bx = r - by * FU_BLOCKS;
    gemm_body<768, 2, false>(query, wT768, b_off, b_attn, 512, fused_h, NROW,
                             bx, by, bsm);
  }
}

// ---------------------------------------------------------------------------
// Fused softmax + deformable bilinear sampling. vproj [B,H,S,32].
//
// Round-15 (on the r14 185.2us structure):
//   * NON-TEMPORAL hints: fused/ref loads + out stores are read/write-once;
//     marking them nt stops them evicting the reusable vh lines from L2.
//     Evidence: FETCH 503MB vs 103MB working set = ~11x vh refetch past L2,
//     driven by 100MB/query-pass of streaming pollution.
//   * Packed (addr,w) LDS table: one ds_read_b64 from tab[hlp][sd*2+rw]
//     replaces two b32 reads + index math per tap (~48 ops/thread saved).
//   Gather loads (vh) stay temporal — they are the reuse stream.
// ---------------------------------------------------------------------------
__global__ __launch_bounds__(256, 4) void msda_sample(
    const _Float16* __restrict__ vproj,     // [B,H,S,32] f16 (+guards)
    const _Float16* __restrict__ fused,     // [B*Q, 768] f16: off(512)|logit(256)
    const float* __restrict__ ref,          // [B*Q, 4, 2] f32
    float* __restrict__ out) {              // [B*Q, 256] f32
  const int lvl_h[NL] = {92, 46, 23, 12};
  const int lvl_w[NL] = {160, 80, 40, 20};
  const int lvl_s[NL] = {0, 14720, 18400, 19320};

  // tab[hlp][sd*2+rw] = { byte-addr (biased +128), weight bits }
  __shared__ __align__(16) intx2 tab[256][4];

  const int t   = threadIdx.x;
  const int blk = blockIdx.x;
  const int b   = blk & 3;             // pins batch to XCD (blk%8 round-robin)
  const int q   = blk >> 2;
  const int row = b * NQ + q;

  const int h  = t >> 5;
  const int lp = t & 31;
  const int l  = lp >> 3;
  const int p  = lp & 7;

  // ---- softmax over the 32 (l,p) logits of this head (xor shuffles) ----
  const float logit =
      (float)__builtin_nontemporal_load(fused + (size_t)row * 768 + 512 + t);
  float mxv = logit;
  #pragma unroll
  for (int m = 1; m < 32; m <<= 1) mxv = fmaxf(mxv, __shfl_xor(mxv, m));
  const float e = __expf(logit - mxv);
  float sum = e;
  #pragma unroll
  for (int m = 1; m < 32; m <<= 1) sum += __shfl_xor(sum, m);
  const float attnw = e / sum;

  // ---- location & bilinear setup ----
  const half2v o2 =
      __builtin_nontemporal_load((const half2v*)(fused + (size_t)row * 768 + 2 * t));
  const float ox = (float)o2[0], oy = (float)o2[1];
  const int z = p & 3;                       // NP=8 split (2,4): z = p % 4
  const floatx2 r2 =
      __builtin_nontemporal_load((const floatx2*)(ref + ((size_t)row * 4 + z) * 2));
  const float rx = r2[0], ry = r2[1];
  const int Wl = lvl_w[l], Hl = lvl_h[l], st = lvl_s[l];

  const float px = fmaf(rx, (float)Wl, ox) - 0.5f;
  const float py = fmaf(ry, (float)Hl, oy) - 0.5f;
  const float x0f = floorf(px), y0f = floorf(py);
  const float wx = px - x0f, wy = py - y0f;
  const int x0 = (int)x0f, y0 = (int)y0f;
  const int x1 = x0 + 1,   y1 = y0 + 1;

  // x: one 128B segment based at xb covers slots xb (left) and xb+1 (right)
  const float mx0 = (x0 >= 0 && x0 < Wl) ? 1.f : 0.f;
  const float mx1 = (x1 >= 0 && x1 < Wl) ? 1.f : 0.f;
  const float my0 = (y0 >= 0 && y0 < Hl) ? 1.f : 0.f;
  const float my1 = (y1 >= 0 && y1 < Hl) ? 1.f : 0.f;
  const int xb  = min(max(x0, -1), Wl - 1);          // guard pages cover x=-1/W
  const int cy0 = min(max(y0, 0), Hl - 1);
  const int cy1 = min(max(y1, 0), Hl - 1);

  const int bh   = b * NH + h;
  const int lbase = bh * S_TOTAL + st;
  const float wlc = attnw * (1.f - wx) * mx0;
  const float wrc = attnw * wx * mx1;

  // byte addresses, biased +128 (guard pages cover x=-1; vb cancels bias)
  const int aTb = (lbase + cy0 * Wl + xb) * 64 + 128;
  const int aBb = (lbase + cy1 * Wl + xb) * 64 + 128;
  intx4 e0, e1;
  e0[0] = aTb; e0[1] = __float_as_int(wlc * (1.f - wy) * my0);
  e0[2] = aBb; e0[3] = __float_as_int(wlc * wy * my1);
  e1[0] = aTb; e1[1] = __float_as_int(wrc * (1.f - wy) * my0);
  e1[2] = aBb; e1[3] = __float_as_int(wrc * wy * my1);
  *(intx4*)&tab[t][0] = e0;   // k=0 (sd0,rw0), k=1 (sd0,rw1)
  *(intx4*)&tab[t][2] = e1;   // k=2 (sd1,rw0), k=3 (sd1,rw1)
  __syncthreads();

  // ---- phase 2: lane g = (pg, rw, c3) within head group ----
  // c3 = 16B chunk of the 128B row (sd = c3>>2, channel oct = c3&3);
  // rw = top/bottom row; pg = lp parity.
  const int g  = t & 31;
  const int c3 = g & 7;
  const int rw = (g >> 3) & 1;
  const int pg = g >> 4;
  const uint32_t cofb = (uint32_t)(c3 << 4);      // byte offset within row
  const char* vb = (const char*)vproj - 128;      // cancels the +128 bias
  const intx2* tp = &tab[(h << 5) + pg][((c3 >> 2) << 1) + rw];

  // load everything first (compiler schedules ~8-deep), then fma
  half8 v[16];
  float w[16];
  #pragma unroll
  for (int i = 0; i < 16; ++i) {
    const intx2 ee = tp[i << 3];                  // ds_read_b64, offset i*64
    w[i] = __int_as_float(ee[1]);
    v[i] = *(const half8*)(vb + ((uint32_t)ee[0] + cofb));
  }

  float a0 = 0.f, a1 = 0.f, a2 = 0.f, a3 = 0.f;
  float a4 = 0.f, a5 = 0.f, a6 = 0.f, a7 = 0.f;
  #pragma unroll
  for (int i = 0; i < 16; ++i) {
    a0 = fmaf(w[i], (float)v[i][0], a0); a1 = fmaf(w[i], (float)v[i][1], a1);
    a2 = fmaf(w[i], (float)v[i][2], a2); a3 = fmaf(w[i], (float)v[i][3], a3);
    a4 = fmaf(w[i], (float)v[i][4], a4); a5 = fmaf(w[i], (float)v[i][5], a5);
    a6 = fmaf(w[i], (float)v[i][6], a6); a7 = fmaf(w[i], (float)v[i][7], a7);
  }

  // reduce over side (xor 4), row (xor 8), parity (xor 16)
  #pragma unroll
  for (int m = 4; m <= 16; m <<= 1) {
    a0 += __shfl_xor(a0, m); a1 += __shfl_xor(a1, m);
    a2 += __shfl_xor(a2, m); a3 += __shfl_xor(a3, m);
    a4 += __shfl_xor(a4, m); a5 += __shfl_xor(a5, m);
    a6 += __shfl_xor(a6, m); a7 += __shfl_xor(a7, m);
  }

  if (g < 4) {    // sd==0, rw==0, pg==0: 4 lanes own the 4 channel octs
    float* op = out + (size_t)row * 256 + (h << 5) + (g << 3);
    floatx4 o0; o0[0] = a0; o0[1] = a1; o0[2] = a2; o0[3] = a3;
    floatx4 o1; o1[0] = a4; o1[1] = a5; o1[2] = a6; o1[3] = a7;
    __builtin_nontemporal_store(o0, (floatx4*)op);
    __builtin_nontemporal_store(o1, (floatx4*)(op + 4));
  }
}

extern "C" void kernel_launch(void* const* d_in, const int* in_sizes, int n_in,
                              void* d_out, int out_size, void* d_ws, size_t ws_size,
                              hipStream_t stream) {
  const float* query  = (const float*)d_in[0];  // [4,10000,256]
  const float* value  = (const float*)d_in[1];  // [4,19560,256]
  const float* refpts = (const float*)d_in[2];  // [4,10000,4,2]
  const float* w_off  = (const float*)d_in[3];  // [256,512]
  const float* b_off  = (const float*)d_in[4];  // [512]
  const float* w_attn = (const float*)d_in[5];  // [256,256]
  const float* b_attn = (const float*)d_in[6];  // [256]
  const float* w_val  = (const float*)d_in[7];  // [256,256]
  const float* b_val  = (const float*)d_in[8];  // [256]
  float* out = (float*)d_out;

  // workspace layout (16B-multiple segments; 256B guards around vh for the
  // x=-1 / x=W edge reads, whose weights are zero)
  char* p = (char*)d_ws;
  p += 256;                                                         // front guard
  _Float16* vh    = (_Float16*)p;  p += (size_t)VROWS * 256 * 2;    // 40.1 MB
  p += 256;                                                         // back guard
  _Float16* wT768 = (_Float16*)p;  p += (size_t)768 * 256 * 2;      // swizzled
  _Float16* wvaT  = (_Float16*)p;  p += (size_t)256 * 256 * 2;      // swizzled
  _Float16* fused_h = (_Float16*)p; p += (size_t)NROW * 768 * 2;    // 61.4 MB

  // prep: all weight transposes in one launch
  prep_weights<<<1024, 256, 0, stream>>>(w_off, w_attn, w_val, wT768, wvaT);

  // both GEMMs in ONE launch: vh blocks [0,612), fused blocks [612,1238)
  gemm_merged<<<dim3(VH_BLOCKS + 2 * FU_BLOCKS), 256, 0, stream>>>(
      value, query, wvaT, wT768, b_val, b_off, b_attn, vh, fused_h);

  // softmax + sample + weighted sum
  msda_sample<<<dim3(NROW), 256, 0, stream>>>(vh, fused_h, refpts, out);
}